// Round 11
// baseline (465.884 us; speedup 1.0000x reference)
//
#include <hip/hip_runtime.h>
#include <math.h>

// Problem constants (B=2, L=2048, H=1024, d_inner=2048, d_state=16, d_conv=4)
#define BATCH 2
#define LSEQ  2048
#define HDIM  1024
#define DI    2048
#define DS    16
#define NPROJ 2080          // 2*DS + DI
#define TOK   4096          // BATCH*LSEQ
#define NCH   64            // scan chunks
#define CLEN  32            // LSEQ / NCH

typedef _Float16 f16;
typedef _Float16 f16x8 __attribute__((ext_vector_type(8)));
typedef _Float16 f16x4 __attribute__((ext_vector_type(4)));
typedef float    f32x4 __attribute__((ext_vector_type(4)));

__device__ __forceinline__ float siluf(float v) { return v / (1.f + __expf(-v)); }
__device__ __forceinline__ float softplusf(float v) {
  return v > 20.f ? v : log1pf(__expf(v));
}

// async global->LDS, 16B per lane. LDS dest must be wave-uniform base + lane*16.
__device__ __forceinline__ void gload16(const void* g, void* l) {
  __builtin_amdgcn_global_load_lds(
      (const __attribute__((address_space(1))) void*)g,
      (__attribute__((address_space(3))) void*)l, 16, 0, 0);
}

// ---------------- weight transpose+cast: Wt[c][r] = (f16)W[r][c] ----------------
__global__ __launch_bounds__(256) void k_transpose(
    const float* __restrict__ W, f16* __restrict__ Wt, int R, int C) {
  __shared__ float t[32][33];
  int c0 = blockIdx.x * 32, r0 = blockIdx.y * 32;
  int tx = threadIdx.x & 31, ty = threadIdx.x >> 5;  // 32 x 8
#pragma unroll
  for (int i = 0; i < 4; ++i) {
    int r = ty + i * 8;
    t[r][tx] = W[(size_t)(r0 + r) * C + c0 + tx];
  }
  __syncthreads();
#pragma unroll
  for (int i = 0; i < 4; ++i) {
    int r = ty + i * 8;  // row in Wt tile (= col in W)
    Wt[(size_t)(c0 + r) * R + r0 + tx] = (f16)t[tx][r];
  }
}

// ---------------- RMSNorm -> f16 ----------------
__global__ __launch_bounds__(256) void k_rmsnorm(
    const float* __restrict__ x, const float* __restrict__ w, f16* __restrict__ h) {
  int t = blockIdx.x;
  int tid = threadIdx.x;
  float4 v = reinterpret_cast<const float4*>(x + (size_t)t * HDIM)[tid];
  float ss = v.x * v.x + v.y * v.y + v.z * v.z + v.w * v.w;
#pragma unroll
  for (int off = 32; off; off >>= 1) ss += __shfl_down(ss, off, 64);
  __shared__ float sred[4];
  if ((tid & 63) == 0) sred[tid >> 6] = ss;
  __syncthreads();
  float tot = sred[0] + sred[1] + sred[2] + sred[3];
  float scale = rsqrtf(tot * (1.f / HDIM) + 1e-6f);
  float4 wv = reinterpret_cast<const float4*>(w)[tid];
  f16x4 o;
  o[0] = (f16)(v.x * scale * wv.x);
  o[1] = (f16)(v.y * scale * wv.y);
  o[2] = (f16)(v.z * scale * wv.z);
  o[3] = (f16)(v.w * scale * wv.w);
  *reinterpret_cast<f16x4*>(h + (size_t)t * HDIM + tid * 4) = o;
}

// ---------------- f16 MFMA GEMM, 2-phase double-buffered pipeline ----------------
// C[M,N](f32) = A[M,K](f16) @ Bt[N,K](f16)^T. 128x128 tile, BK=32, 4 waves.
// One raw barrier per K-tile; next tile's global_load_lds issued BEFORE compute,
// vmcnt(0) only AFTER the MFMAs (loads hide under compute). XCD-swizzled blocks.
// MODE 1: softplus cols>=32 -> C. MODE 2: C = acc + R. MODE 3: f16 split store
// (cols<DI -> Ox, else Oz).
template <int MODE>
__global__ __launch_bounds__(256) void k_mgemm(
    const f16* __restrict__ A, const f16* __restrict__ Bt,
    float* __restrict__ C, const float* __restrict__ R,
    f16* __restrict__ Ox, f16* __restrict__ Oz,
    int M, int N, int K) {
  __shared__ __align__(16) f16 At[2 * 128 * 32];   // 16KB
  __shared__ __align__(16) f16 Bs[2 * 128 * 32];   // 16KB
  const int tid = threadIdx.x;
  const int lane = tid & 63;
  const int w = tid >> 6;
  const int wm = w >> 1, wn = w & 1;

  // bijective XCD swizzle (m204): contiguous grid chunk per XCD -> A-panel L2 reuse
  const int gx = gridDim.x;
  const int nwg = gx * gridDim.y;
  const int bid = blockIdx.y * gx + blockIdx.x;
  const int q = nwg >> 3, r = nwg & 7;
  const int xcd = bid & 7, idx = bid >> 3;
  const int swzb = (xcd < r ? xcd * (q + 1) : r * (q + 1) + (xcd - r) * q) + idx;
  const int m0 = (swzb / gx) * 128, n0 = (swzb % gx) * 128;
  const int Nlim = N - 1;

  // ---- staging setup (constant per thread) ----
  const int ls = lane >> 2;                 // row within 16-row chunk
  const int kq = lane & 3;                  // 16B quad
  const int rowA0 = w * 16 + ls;            // chunk w      (rows 0..63)
  const int rowA1 = rowA0 + 64;             // chunk w+4    (rows 64..127)
  const int swz = ((kq << 4) ^ ((rowA0 & 3) << 4)) >> 1;  // f16 elems (rowA1&3 == rowA0&3)
  const f16* gA0 = A + (size_t)(m0 + rowA0) * K + swz;
  const f16* gA1 = A + (size_t)(m0 + rowA1) * K + swz;
  int rb0 = n0 + rowA0; rb0 = rb0 > Nlim ? Nlim : rb0;
  int rb1 = n0 + rowA1; rb1 = rb1 > Nlim ? Nlim : rb1;
  const f16* gB0 = Bt + (size_t)rb0 * K + swz;
  const f16* gB1 = Bt + (size_t)rb1 * K + swz;
  const int ld0 = w * 1024 + (lane << 4);         // byte offset, chunk w
  const int ld1 = (w + 4) * 1024 + (lane << 4);   // byte offset, chunk w+4

  // ---- fragment read offsets (bytes, constant) ----
  const int fr = lane & 15;
  const int kgb = (lane >> 4) << 4;
  int offA[4], offB[4];
#pragma unroll
  for (int i = 0; i < 4; ++i) {
    int ra = wm * 64 + i * 16 + fr;
    offA[i] = ra * 64 + (kgb ^ ((ra & 3) << 4));
    int rbx = wn * 64 + i * 16 + fr;
    offB[i] = rbx * 64 + (kgb ^ ((rbx & 3) << 4));
  }

  f32x4 acc[4][4];
#pragma unroll
  for (int i = 0; i < 4; ++i)
#pragma unroll
    for (int j = 0; j < 4; ++j) acc[i][j] = (f32x4){0.f, 0.f, 0.f, 0.f};

  const int nt = K >> 5;  // K/32, always even here (32 or 64)

#define STAGE(buf, tt)                                                   \
  {                                                                      \
    const int ke = (tt) << 5;                                            \
    gload16(gA0 + ke, (char*)At + (buf)*8192 + ld0);                     \
    gload16(gA1 + ke, (char*)At + (buf)*8192 + ld1);                     \
    gload16(gB0 + ke, (char*)Bs + (buf)*8192 + ld0);                     \
    gload16(gB1 + ke, (char*)Bs + (buf)*8192 + ld1);                     \
  }

#define COMPUTE(buf)                                                     \
  {                                                                      \
    const char* bA = (const char*)At + (buf)*8192;                       \
    const char* bB = (const char*)Bs + (buf)*8192;                       \
    f16x8 a[4], b[4];                                                    \
    _Pragma("unroll") for (int mi = 0; mi < 4; ++mi)                     \
        a[mi] = *(const f16x8*)(bA + offA[mi]);                          \
    _Pragma("unroll") for (int ni = 0; ni < 4; ++ni)                     \
        b[ni] = *(const f16x8*)(bB + offB[ni]);                          \
    _Pragma("unroll") for (int mi = 0; mi < 4; ++mi)                     \
        _Pragma("unroll") for (int ni = 0; ni < 4; ++ni)                 \
            acc[mi][ni] = __builtin_amdgcn_mfma_f32_16x16x32_f16(        \
                a[mi], b[ni], acc[mi][ni], 0, 0, 0);                     \
  }

  // prologue
  STAGE(0, 0);
  asm volatile("s_waitcnt vmcnt(0)" ::: "memory");
  __builtin_amdgcn_s_barrier();

  for (int t = 0; t < nt; t += 2) {
    if (t + 1 < nt) STAGE(1, t + 1);
    COMPUTE(0);
    asm volatile("s_waitcnt vmcnt(0)" ::: "memory");
    __builtin_amdgcn_s_barrier();
    if (t + 2 < nt) STAGE(0, t + 2);
    COMPUTE(1);
    asm volatile("s_waitcnt vmcnt(0)" ::: "memory");
    __builtin_amdgcn_s_barrier();
  }
#undef STAGE
#undef COMPUTE

  // ---- epilogue: D col = lane&15, row = (lane>>4)*4 + j ----
  const int r4 = (lane >> 4) << 2;
#pragma unroll
  for (int mi = 0; mi < 4; ++mi) {
#pragma unroll
    for (int ni = 0; ni < 4; ++ni) {
      int col = n0 + wn * 64 + ni * 16 + fr;
      if (col < N) {
        int mrow = m0 + wm * 64 + mi * 16 + r4;
#pragma unroll
        for (int j = 0; j < 4; ++j) {
          float v = acc[mi][ni][j];
          if (MODE == 1) {
            if (col >= 2 * DS) v = softplusf(v);
            C[(size_t)(mrow + j) * N + col] = v;
          } else if (MODE == 2) {
            size_t o = (size_t)(mrow + j) * N + col;
            C[o] = v + R[o];
          } else {  // MODE 3: f16 split store
            if (col < DI) Ox[(size_t)(mrow + j) * DI + col] = (f16)v;
            else          Oz[(size_t)(mrow + j) * DI + col - DI] = (f16)v;
          }
        }
      }
    }
  }
}

// ------------- causal depthwise conv (k=4) + bias + SiLU, f16 in/out -------------
__global__ __launch_bounds__(256) void k_conv(
    const f16* __restrict__ xr, const float* __restrict__ cw,
    const float* __restrict__ cb, f16* __restrict__ xs) {
  size_t idx = (size_t)blockIdx.x * 256 + threadIdx.x;  // over TOK*DI
  int d = (int)(idx & (DI - 1));
  size_t tf = idx >> 11;                 // flat token b*L + t
  int t = (int)(tf & (LSEQ - 1));
  const f16* base = xr + tf * DI + d;
  float acc = cb[d];
  float w0 = cw[d * 4 + 0], w1 = cw[d * 4 + 1], w2 = cw[d * 4 + 2], w3 = cw[d * 4 + 3];
  acc = fmaf(w3, (float)base[0], acc);
  if (t >= 1) acc = fmaf(w2, (float)base[-(ptrdiff_t)DI], acc);
  if (t >= 2) acc = fmaf(w1, (float)base[-(ptrdiff_t)(2 * DI)], acc);
  if (t >= 3) acc = fmaf(w0, (float)base[-(ptrdiff_t)(3 * DI)], acc);
  xs[idx] = (f16)siluf(acc);
}

// ======================= chunked parallel selective scan =======================
// Thread per (b,d,chunk); all DS=16 states in registers.
// State buffers layout: idx = ((c*BATCH + b)*DI + d)*DS + n = gid*DS + n.

// Phase A: per-chunk scan from h=0; emit P[n] = prod(da), h_end[n].
__global__ __launch_bounds__(256) void k_scanA(
    const float* __restrict__ proj, const f16* __restrict__ xs,
    const float* __restrict__ A_log,
    float* __restrict__ Atot, float* __restrict__ Hend) {
  int gid = blockIdx.x * 256 + threadIdx.x;   // (c*BATCH+b)*DI + d
  int d = gid & (DI - 1);
  int b = (gid >> 11) & (BATCH - 1);
  int c = gid >> 12;
  float Ad[DS];
  {
    const float4* ap = reinterpret_cast<const float4*>(A_log + (size_t)d * DS);
#pragma unroll
    for (int i = 0; i < 4; ++i) {
      float4 v = ap[i];
      Ad[4 * i + 0] = -__expf(v.x);
      Ad[4 * i + 1] = -__expf(v.y);
      Ad[4 * i + 2] = -__expf(v.z);
      Ad[4 * i + 3] = -__expf(v.w);
    }
  }
  float h[DS], P[DS];
#pragma unroll
  for (int n = 0; n < DS; ++n) { h[n] = 0.f; P[n] = 1.f; }
  const float* prow = proj + ((size_t)b * LSEQ + (size_t)c * CLEN) * NPROJ;
  const f16* xrow = xs + ((size_t)b * LSEQ + (size_t)c * CLEN) * DI + d;
  for (int t = 0; t < CLEN; ++t) {
    const float* pr = prow + (size_t)t * NPROJ;
    float dt = pr[2 * DS + d];
    float xv = (float)xrow[(size_t)t * DI];
    float Bv[DS];
    {
      const float4* p4 = reinterpret_cast<const float4*>(pr);
#pragma unroll
      for (int i = 0; i < 4; ++i) {
        float4 v = p4[i];
        Bv[4 * i + 0] = v.x; Bv[4 * i + 1] = v.y;
        Bv[4 * i + 2] = v.z; Bv[4 * i + 3] = v.w;
      }
    }
    float dxv = dt * xv;
#pragma unroll
    for (int n = 0; n < DS; ++n) {
      float da = __expf(dt * Ad[n]);
      P[n] *= da;
      h[n] = fmaf(da, h[n], dxv * Bv[n]);
    }
  }
  float4* ao = reinterpret_cast<float4*>(Atot + (size_t)gid * DS);
  float4* ho = reinterpret_cast<float4*>(Hend + (size_t)gid * DS);
#pragma unroll
  for (int i = 0; i < 4; ++i) {
    ao[i] = make_float4(P[4 * i], P[4 * i + 1], P[4 * i + 2], P[4 * i + 3]);
    ho[i] = make_float4(h[4 * i], h[4 * i + 1], h[4 * i + 2], h[4 * i + 3]);
  }
}

// Phase B: sequential stitch over chunks; writes Hin IN PLACE over Atot.
__global__ __launch_bounds__(256) void k_scanB(
    float* __restrict__ Atot, const float* __restrict__ Hend) {
  int gid = blockIdx.x * 256 + threadIdx.x;  // (b*DI+d)*DS + n, 65536 total
  float h = 0.f;
#pragma unroll
  for (int c = 0; c < NCH; ++c) {
    size_t idx = (size_t)c * (BATCH * DI * DS) + gid;
    float P = Atot[idx];
    Atot[idx] = h;                 // h_in for chunk c
    h = fmaf(P, h, Hend[idx]);
  }
}

// Phase C: re-scan chunk from Hin (in Atot buffer), reduce over n, fuse gate.
__global__ __launch_bounds__(256) void k_scanC(
    const float* __restrict__ proj, const f16* __restrict__ xs,
    const f16* __restrict__ z16, const float* __restrict__ A_log,
    const float* __restrict__ Dp, const float* __restrict__ Hin,
    f16* __restrict__ yg) {
  int gid = blockIdx.x * 256 + threadIdx.x;   // (c*BATCH+b)*DI + d
  int d = gid & (DI - 1);
  int b = (gid >> 11) & (BATCH - 1);
  int c = gid >> 12;
  float Ad[DS];
  {
    const float4* ap = reinterpret_cast<const float4*>(A_log + (size_t)d * DS);
#pragma unroll
    for (int i = 0; i < 4; ++i) {
      float4 v = ap[i];
      Ad[4 * i + 0] = -__expf(v.x);
      Ad[4 * i + 1] = -__expf(v.y);
      Ad[4 * i + 2] = -__expf(v.z);
      Ad[4 * i + 3] = -__expf(v.w);
    }
  }
  float h[DS];
  {
    const float4* hi = reinterpret_cast<const float4*>(Hin + (size_t)gid * DS);
#pragma unroll
    for (int i = 0; i < 4; ++i) {
      float4 v = hi[i];
      h[4 * i + 0] = v.x; h[4 * i + 1] = v.y;
      h[4 * i + 2] = v.z; h[4 * i + 3] = v.w;
    }
  }
  float Dd = Dp[d];
  const float* prow = proj + ((size_t)b * LSEQ + (size_t)c * CLEN) * NPROJ;
  const f16* xrow = xs + ((size_t)b * LSEQ + (size_t)c * CLEN) * DI + d;
  const f16* zrow = z16 + ((size_t)b * LSEQ + (size_t)c * CLEN) * DI + d;
  f16* yrow = yg + ((size_t)b * LSEQ + (size_t)c * CLEN) * DI + d;
  for (int t = 0; t < CLEN; ++t) {
    const float* pr = prow + (size_t)t * NPROJ;
    float dt = pr[2 * DS + d];
    float xv = (float)xrow[(size_t)t * DI];
    float Bv[DS], Cv[DS];
    {
      const float4* p4 = reinterpret_cast<const float4*>(pr);
#pragma unroll
      for (int i = 0; i < 4; ++i) {
        float4 v = p4[i];
        Bv[4 * i + 0] = v.x; Bv[4 * i + 1] = v.y;
        Bv[4 * i + 2] = v.z; Bv[4 * i + 3] = v.w;
      }
#pragma unroll
      for (int i = 0; i < 4; ++i) {
        float4 v = p4[4 + i];
        Cv[4 * i + 0] = v.x; Cv[4 * i + 1] = v.y;
        Cv[4 * i + 2] = v.z; Cv[4 * i + 3] = v.w;
      }
    }
    float dxv = dt * xv;
    float y = 0.f;
#pragma unroll
    for (int n = 0; n < DS; ++n) {
      float da = __expf(dt * Ad[n]);
      h[n] = fmaf(da, h[n], dxv * Bv[n]);
      y = fmaf(h[n], Cv[n], y);
    }
    float z = (float)zrow[(size_t)t * DI];
    yrow[(size_t)t * DI] = (f16)((y + Dd * xv) * siluf(z));
  }
}

extern "C" void kernel_launch(void* const* d_in, const int* in_sizes, int n_in,
                              void* d_out, int out_size, void* d_ws, size_t ws_size,
                              hipStream_t stream) {
  const float* x       = (const float*)d_in[0];
  const float* norm_w  = (const float*)d_in[1];
  const float* w_in    = (const float*)d_in[2];
  const float* conv_w  = (const float*)d_in[3];
  const float* conv_b  = (const float*)d_in[4];
  const float* w_xproj = (const float*)d_in[5];
  const float* A_log   = (const float*)d_in[6];
  const float* D_param = (const float*)d_in[7];
  const float* w_out   = (const float*)d_in[8];
  float* out = (float*)d_out;

  // workspace layout (bytes), ~157 MiB total
  char* ws = (char*)d_ws;
  size_t off = 0;
  float* proj  = (float*)(ws + off); off += (size_t)TOK * NPROJ * 4;     // 32.5 MiB
  f16*   xr16  = (f16*)(ws + off);   off += (size_t)TOK * DI * 2;        // 16 MiB (pre-conv x)
  f16*   z16   = (f16*)(ws + off);   off += (size_t)TOK * DI * 2;        // 16 MiB
  f16*   h16   = (f16*)(ws + off);   off += (size_t)TOK * HDIM * 2;      // 8 MiB
  f16*   xs16  = (f16*)(ws + off);   off += (size_t)TOK * DI * 2;        // 16 MiB
  f16*   yg16  = (f16*)(ws + off);   off += (size_t)TOK * DI * 2;        // 16 MiB
  f16*   winT  = (f16*)(ws + off);   off += (size_t)2 * DI * HDIM * 2;   // 8 MiB
  f16*   wxT   = (f16*)(ws + off);   off += (size_t)NPROJ * DI * 2;      // 8.5 MiB
  f16*   woT   = (f16*)(ws + off);   off += (size_t)HDIM * DI * 2;       // 4 MiB
  const size_t SCN = (size_t)NCH * BATCH * DI * DS;                      // 4M elems
  float* Atot  = (float*)(ws + off); off += SCN * 4;                     // 16 MiB (->Hin)
  float* Hend  = (float*)(ws + off); off += SCN * 4;                     // 16 MiB

  // 0. weight transpose+cast (f16, [N][K] row-major)
  k_transpose<<<dim3((2 * DI) / 32, HDIM / 32), 256, 0, stream>>>(w_in, winT, HDIM, 2 * DI);
  k_transpose<<<dim3(NPROJ / 32, DI / 32), 256, 0, stream>>>(w_xproj, wxT, DI, NPROJ);
  k_transpose<<<dim3(HDIM / 32, DI / 32), 256, 0, stream>>>(w_out, woT, DI, HDIM);
  // 1. RMSNorm -> h16
  k_rmsnorm<<<TOK, 256, 0, stream>>>(x, norm_w, h16);
  // 2. [xr16|z16] = h @ w_in   (4096x1024 @ 1024x4096, f16 split store)
  k_mgemm<3><<<dim3((2 * DI) / 128, TOK / 128), 256, 0, stream>>>(
      h16, winT, nullptr, nullptr, xr16, z16, TOK, 2 * DI, HDIM);
  // 3. xs16 = silu(conv(xr16) + b)
  k_conv<<<(TOK * DI) / 256, 256, 0, stream>>>(xr16, conv_w, conv_b, xs16);
  // 4. proj = xs @ w_xproj (softplus on cols>=32), N=2080 -> 17 n-tiles
  k_mgemm<1><<<dim3(17, TOK / 128), 256, 0, stream>>>(
      xs16, wxT, proj, nullptr, nullptr, nullptr, TOK, NPROJ, DI);
  // 5. chunked scan: A (per-chunk, reg-state), B (in-place stitch), C (+gate)
  const int NTH = NCH * BATCH * DI;                     // 262144 threads
  k_scanA<<<NTH / 256, 256, 0, stream>>>(proj, xs16, A_log, Atot, Hend);
  k_scanB<<<(BATCH * DI * DS) / 256, 256, 0, stream>>>(Atot, Hend);
  k_scanC<<<NTH / 256, 256, 0, stream>>>(proj, xs16, z16, A_log, D_param,
                                         Atot, yg16);
  // 6. out = x + yg @ w_out
  k_mgemm<2><<<dim3(HDIM / 128, TOK / 128), 256, 0, stream>>>(
      yg16, woT, out, x, nullptr, nullptr, TOK, HDIM, DI);
}

// Round 12
// 440.405 us; speedup vs baseline: 1.0579x; 1.0579x over previous
//
#include <hip/hip_runtime.h>
#include <math.h>

// Problem constants (B=2, L=2048, H=1024, d_inner=2048, d_state=16, d_conv=4)
#define BATCH 2
#define LSEQ  2048
#define HDIM  1024
#define DI    2048
#define DS    16
#define NPROJ 2080          // 2*DS + DI
#define TOK   4096          // BATCH*LSEQ
#define NCH   64            // scan chunks
#define CLEN  32            // LSEQ / NCH

typedef _Float16 f16;
typedef _Float16 f16x8 __attribute__((ext_vector_type(8)));
typedef _Float16 f16x4 __attribute__((ext_vector_type(4)));
typedef float    f32x4 __attribute__((ext_vector_type(4)));

__device__ __forceinline__ float siluf(float v) { return v / (1.f + __expf(-v)); }
__device__ __forceinline__ float softplusf(float v) {
  return v > 20.f ? v : log1pf(__expf(v));
}

// async global->LDS, 16B per lane. LDS dest must be wave-uniform base + lane*16.
__device__ __forceinline__ void gload16(const void* g, void* l) {
  __builtin_amdgcn_global_load_lds(
      (const __attribute__((address_space(1))) void*)g,
      (__attribute__((address_space(3))) void*)l, 16, 0, 0);
}

// ---------------- weight transpose+cast: Wt[c][r] = (f16)W[r][c] ----------------
__global__ __launch_bounds__(256) void k_transpose(
    const float* __restrict__ W, f16* __restrict__ Wt, int R, int C) {
  __shared__ float t[32][33];
  int c0 = blockIdx.x * 32, r0 = blockIdx.y * 32;
  int tx = threadIdx.x & 31, ty = threadIdx.x >> 5;  // 32 x 8
#pragma unroll
  for (int i = 0; i < 4; ++i) {
    int r = ty + i * 8;
    t[r][tx] = W[(size_t)(r0 + r) * C + c0 + tx];
  }
  __syncthreads();
#pragma unroll
  for (int i = 0; i < 4; ++i) {
    int r = ty + i * 8;  // row in Wt tile (= col in W)
    Wt[(size_t)(c0 + r) * R + r0 + tx] = (f16)t[tx][r];
  }
}

// ---------------- RMSNorm -> f16 ----------------
__global__ __launch_bounds__(256) void k_rmsnorm(
    const float* __restrict__ x, const float* __restrict__ w, f16* __restrict__ h) {
  int t = blockIdx.x;
  int tid = threadIdx.x;
  float4 v = reinterpret_cast<const float4*>(x + (size_t)t * HDIM)[tid];
  float ss = v.x * v.x + v.y * v.y + v.z * v.z + v.w * v.w;
#pragma unroll
  for (int off = 32; off; off >>= 1) ss += __shfl_down(ss, off, 64);
  __shared__ float sred[4];
  if ((tid & 63) == 0) sred[tid >> 6] = ss;
  __syncthreads();
  float tot = sred[0] + sred[1] + sred[2] + sred[3];
  float scale = rsqrtf(tot * (1.f / HDIM) + 1e-6f);
  float4 wv = reinterpret_cast<const float4*>(w)[tid];
  f16x4 o;
  o[0] = (f16)(v.x * scale * wv.x);
  o[1] = (f16)(v.y * scale * wv.y);
  o[2] = (f16)(v.z * scale * wv.z);
  o[3] = (f16)(v.w * scale * wv.w);
  *reinterpret_cast<f16x4*>(h + (size_t)t * HDIM + tid * 4) = o;
}

// ---------------- f16 MFMA GEMM: C[M,N] = A[M,K] @ Bt[N,K]^T ----------------
// Tile BM x 128, BM = MI*32 (MI=4: 128, MI=2: 64 -> 2x the blocks for small-N
// GEMMs; blocks/CU is the latency-hiding lever per m102 shape curve).
// 4 waves as 2x2; wave tile (MI*16) x 64; MI x 4 frags of 16x16x32.
// Single-buffer LDS + __syncthreads (proven round-9 body). XCD-swizzled bid.
// MODE 1: softplus cols>=32 -> C. MODE 2: C = acc + R. MODE 3: f16 split store.
template <int MODE, int MI>
__global__ __launch_bounds__(256) void k_mgemm(
    const f16* __restrict__ A, const f16* __restrict__ Bt,
    float* __restrict__ C, const float* __restrict__ R,
    f16* __restrict__ Ox, f16* __restrict__ Oz,
    int M, int N, int K) {
  constexpr int BM = MI * 32;
  constexpr int NA = MI / 2;  // A-chunk loads per thread (1 or 2)
  __shared__ __align__(16) f16 At[BM * 32];
  __shared__ __align__(16) f16 Bs[128 * 32];
  const int tid = threadIdx.x;
  const int lane = tid & 63;
  const int w = tid >> 6;
  const int wm = w >> 1, wn = w & 1;

  // bijective XCD swizzle (m204): contiguous grid chunk per XCD
  const int gx = gridDim.x;
  const int nwg = gx * gridDim.y;
  const int bid = blockIdx.y * gx + blockIdx.x;
  const int q = nwg >> 3, r = nwg & 7;
  const int xcd = bid & 7, ix = bid >> 3;
  const int swzb = (xcd < r ? xcd * (q + 1) : r * (q + 1) + (xcd - r) * q) + ix;
  const int m0 = (swzb / gx) * BM, n0 = (swzb % gx) * 128;
  const int Nlim = N - 1;

  // ---- staging setup (constant per thread) ----
  const int ls = lane >> 2;                 // row within 16-row chunk
  const int kq = lane & 3;                  // 16B quad
  const int lofs = lane << 4;
  const f16* gA[NA];
  int ldA[NA];
#pragma unroll
  for (int i = 0; i < NA; ++i) {
    int c = w + i * 4;                      // NA=1: chunks 0..3; NA=2: 0..7
    int row = c * 16 + ls;
    int swz = ((kq << 4) ^ ((row & 3) << 4)) >> 1;
    gA[i] = A + (size_t)(m0 + row) * K + swz;
    ldA[i] = c * 1024 + lofs;
  }
  const f16* gB[2];
  int ldB[2];
#pragma unroll
  for (int i = 0; i < 2; ++i) {
    int c = w + i * 4;                      // 8 chunks (128 rows)
    int row = c * 16 + ls;
    int swz = ((kq << 4) ^ ((row & 3) << 4)) >> 1;
    int rb = n0 + row; rb = rb > Nlim ? Nlim : rb;  // clamp ragged N-tile
    gB[i] = Bt + (size_t)rb * K + swz;
    ldB[i] = c * 1024 + lofs;
  }

  // ---- fragment read offsets (bytes, constant) ----
  const int fr = lane & 15;
  const int kgb = (lane >> 4) << 4;
  int offA[MI], offB[4];
#pragma unroll
  for (int i = 0; i < MI; ++i) {
    int ra = wm * (MI * 16) + i * 16 + fr;
    offA[i] = ra * 64 + (kgb ^ ((ra & 3) << 4));
  }
#pragma unroll
  for (int i = 0; i < 4; ++i) {
    int rbw = wn * 64 + i * 16 + fr;
    offB[i] = rbw * 64 + (kgb ^ ((rbw & 3) << 4));
  }

  f32x4 acc[MI][4];
#pragma unroll
  for (int i = 0; i < MI; ++i)
#pragma unroll
    for (int j = 0; j < 4; ++j) acc[i][j] = (f32x4){0.f, 0.f, 0.f, 0.f};

  const int nt = K >> 5;
  for (int t = 0; t < nt; ++t) {
    const int ke = t << 5;
#pragma unroll
    for (int i = 0; i < NA; ++i) gload16(gA[i] + ke, (char*)At + ldA[i]);
#pragma unroll
    for (int i = 0; i < 2; ++i) gload16(gB[i] + ke, (char*)Bs + ldB[i]);
    __syncthreads();  // drains vmcnt -> LDS writes visible
    f16x8 a[MI], b[4];
#pragma unroll
    for (int mi = 0; mi < MI; ++mi) a[mi] = *(const f16x8*)((char*)At + offA[mi]);
#pragma unroll
    for (int ni = 0; ni < 4; ++ni) b[ni] = *(const f16x8*)((char*)Bs + offB[ni]);
#pragma unroll
    for (int mi = 0; mi < MI; ++mi)
#pragma unroll
      for (int ni = 0; ni < 4; ++ni)
        acc[mi][ni] = __builtin_amdgcn_mfma_f32_16x16x32_f16(
            a[mi], b[ni], acc[mi][ni], 0, 0, 0);
    __syncthreads();  // protect LDS from next-iter staging
  }

  // ---- epilogue: D col = lane&15, row = (lane>>4)*4 + j ----
  const int r4 = (lane >> 4) << 2;
#pragma unroll
  for (int mi = 0; mi < MI; ++mi) {
#pragma unroll
    for (int ni = 0; ni < 4; ++ni) {
      int col = n0 + wn * 64 + ni * 16 + fr;
      if (col < N) {
        int mrow = m0 + wm * (MI * 16) + mi * 16 + r4;
#pragma unroll
        for (int j = 0; j < 4; ++j) {
          float v = acc[mi][ni][j];
          if (MODE == 1) {
            if (col >= 2 * DS) v = softplusf(v);
            C[(size_t)(mrow + j) * N + col] = v;
          } else if (MODE == 2) {
            size_t o = (size_t)(mrow + j) * N + col;
            C[o] = v + R[o];
          } else {  // MODE 3: f16 split store
            if (col < DI) Ox[(size_t)(mrow + j) * DI + col] = (f16)v;
            else          Oz[(size_t)(mrow + j) * DI + col - DI] = (f16)v;
          }
        }
      }
    }
  }
}

// ------------- causal depthwise conv (k=4) + bias + SiLU, f16 in/out -------------
__global__ __launch_bounds__(256) void k_conv(
    const f16* __restrict__ xr, const float* __restrict__ cw,
    const float* __restrict__ cb, f16* __restrict__ xs) {
  size_t idx = (size_t)blockIdx.x * 256 + threadIdx.x;  // over TOK*DI
  int d = (int)(idx & (DI - 1));
  size_t tf = idx >> 11;                 // flat token b*L + t
  int t = (int)(tf & (LSEQ - 1));
  const f16* base = xr + tf * DI + d;
  float acc = cb[d];
  float w0 = cw[d * 4 + 0], w1 = cw[d * 4 + 1], w2 = cw[d * 4 + 2], w3 = cw[d * 4 + 3];
  acc = fmaf(w3, (float)base[0], acc);
  if (t >= 1) acc = fmaf(w2, (float)base[-(ptrdiff_t)DI], acc);
  if (t >= 2) acc = fmaf(w1, (float)base[-(ptrdiff_t)(2 * DI)], acc);
  if (t >= 3) acc = fmaf(w0, (float)base[-(ptrdiff_t)(3 * DI)], acc);
  xs[idx] = (f16)siluf(acc);
}

// ======================= chunked parallel selective scan =======================
// Thread per (b,d,chunk); all DS=16 states in registers.
// State buffers layout: idx = ((c*BATCH + b)*DI + d)*DS + n = gid*DS + n.

// Phase A: per-chunk scan from h=0; emit P[n] = prod(da), h_end[n].
__global__ __launch_bounds__(256) void k_scanA(
    const float* __restrict__ proj, const f16* __restrict__ xs,
    const float* __restrict__ A_log,
    float* __restrict__ Atot, float* __restrict__ Hend) {
  int gid = blockIdx.x * 256 + threadIdx.x;   // (c*BATCH+b)*DI + d
  int d = gid & (DI - 1);
  int b = (gid >> 11) & (BATCH - 1);
  int c = gid >> 12;
  float Ad[DS];
  {
    const float4* ap = reinterpret_cast<const float4*>(A_log + (size_t)d * DS);
#pragma unroll
    for (int i = 0; i < 4; ++i) {
      float4 v = ap[i];
      Ad[4 * i + 0] = -__expf(v.x);
      Ad[4 * i + 1] = -__expf(v.y);
      Ad[4 * i + 2] = -__expf(v.z);
      Ad[4 * i + 3] = -__expf(v.w);
    }
  }
  float h[DS], P[DS];
#pragma unroll
  for (int n = 0; n < DS; ++n) { h[n] = 0.f; P[n] = 1.f; }
  const float* prow = proj + ((size_t)b * LSEQ + (size_t)c * CLEN) * NPROJ;
  const f16* xrow = xs + ((size_t)b * LSEQ + (size_t)c * CLEN) * DI + d;
  for (int t = 0; t < CLEN; ++t) {
    const float* pr = prow + (size_t)t * NPROJ;
    float dt = pr[2 * DS + d];
    float xv = (float)xrow[(size_t)t * DI];
    float Bv[DS];
    {
      const float4* p4 = reinterpret_cast<const float4*>(pr);
#pragma unroll
      for (int i = 0; i < 4; ++i) {
        float4 v = p4[i];
        Bv[4 * i + 0] = v.x; Bv[4 * i + 1] = v.y;
        Bv[4 * i + 2] = v.z; Bv[4 * i + 3] = v.w;
      }
    }
    float dxv = dt * xv;
#pragma unroll
    for (int n = 0; n < DS; ++n) {
      float da = __expf(dt * Ad[n]);
      P[n] *= da;
      h[n] = fmaf(da, h[n], dxv * Bv[n]);
    }
  }
  float4* ao = reinterpret_cast<float4*>(Atot + (size_t)gid * DS);
  float4* ho = reinterpret_cast<float4*>(Hend + (size_t)gid * DS);
#pragma unroll
  for (int i = 0; i < 4; ++i) {
    ao[i] = make_float4(P[4 * i], P[4 * i + 1], P[4 * i + 2], P[4 * i + 3]);
    ho[i] = make_float4(h[4 * i], h[4 * i + 1], h[4 * i + 2], h[4 * i + 3]);
  }
}

// Phase B: sequential stitch over chunks; writes Hin IN PLACE over Atot.
__global__ __launch_bounds__(256) void k_scanB(
    float* __restrict__ Atot, const float* __restrict__ Hend) {
  int gid = blockIdx.x * 256 + threadIdx.x;  // (b*DI+d)*DS + n, 65536 total
  float h = 0.f;
#pragma unroll
  for (int c = 0; c < NCH; ++c) {
    size_t idx = (size_t)c * (BATCH * DI * DS) + gid;
    float P = Atot[idx];
    Atot[idx] = h;                 // h_in for chunk c
    h = fmaf(P, h, Hend[idx]);
  }
}

// Phase C: re-scan chunk from Hin (in Atot buffer), reduce over n, fuse gate.
__global__ __launch_bounds__(256) void k_scanC(
    const float* __restrict__ proj, const f16* __restrict__ xs,
    const f16* __restrict__ z16, const float* __restrict__ A_log,
    const float* __restrict__ Dp, const float* __restrict__ Hin,
    f16* __restrict__ yg) {
  int gid = blockIdx.x * 256 + threadIdx.x;   // (c*BATCH+b)*DI + d
  int d = gid & (DI - 1);
  int b = (gid >> 11) & (BATCH - 1);
  int c = gid >> 12;
  float Ad[DS];
  {
    const float4* ap = reinterpret_cast<const float4*>(A_log + (size_t)d * DS);
#pragma unroll
    for (int i = 0; i < 4; ++i) {
      float4 v = ap[i];
      Ad[4 * i + 0] = -__expf(v.x);
      Ad[4 * i + 1] = -__expf(v.y);
      Ad[4 * i + 2] = -__expf(v.z);
      Ad[4 * i + 3] = -__expf(v.w);
    }
  }
  float h[DS];
  {
    const float4* hi = reinterpret_cast<const float4*>(Hin + (size_t)gid * DS);
#pragma unroll
    for (int i = 0; i < 4; ++i) {
      float4 v = hi[i];
      h[4 * i + 0] = v.x; h[4 * i + 1] = v.y;
      h[4 * i + 2] = v.z; h[4 * i + 3] = v.w;
    }
  }
  float Dd = Dp[d];
  const float* prow = proj + ((size_t)b * LSEQ + (size_t)c * CLEN) * NPROJ;
  const f16* xrow = xs + ((size_t)b * LSEQ + (size_t)c * CLEN) * DI + d;
  const f16* zrow = z16 + ((size_t)b * LSEQ + (size_t)c * CLEN) * DI + d;
  f16* yrow = yg + ((size_t)b * LSEQ + (size_t)c * CLEN) * DI + d;
  for (int t = 0; t < CLEN; ++t) {
    const float* pr = prow + (size_t)t * NPROJ;
    float dt = pr[2 * DS + d];
    float xv = (float)xrow[(size_t)t * DI];
    float Bv[DS], Cv[DS];
    {
      const float4* p4 = reinterpret_cast<const float4*>(pr);
#pragma unroll
      for (int i = 0; i < 4; ++i) {
        float4 v = p4[i];
        Bv[4 * i + 0] = v.x; Bv[4 * i + 1] = v.y;
        Bv[4 * i + 2] = v.z; Bv[4 * i + 3] = v.w;
      }
#pragma unroll
      for (int i = 0; i < 4; ++i) {
        float4 v = p4[4 + i];
        Cv[4 * i + 0] = v.x; Cv[4 * i + 1] = v.y;
        Cv[4 * i + 2] = v.z; Cv[4 * i + 3] = v.w;
      }
    }
    float dxv = dt * xv;
    float y = 0.f;
#pragma unroll
    for (int n = 0; n < DS; ++n) {
      float da = __expf(dt * Ad[n]);
      h[n] = fmaf(da, h[n], dxv * Bv[n]);
      y = fmaf(h[n], Cv[n], y);
    }
    float z = (float)zrow[(size_t)t * DI];
    yrow[(size_t)t * DI] = (f16)((y + Dd * xv) * siluf(z));
  }
}

extern "C" void kernel_launch(void* const* d_in, const int* in_sizes, int n_in,
                              void* d_out, int out_size, void* d_ws, size_t ws_size,
                              hipStream_t stream) {
  const float* x       = (const float*)d_in[0];
  const float* norm_w  = (const float*)d_in[1];
  const float* w_in    = (const float*)d_in[2];
  const float* conv_w  = (const float*)d_in[3];
  const float* conv_b  = (const float*)d_in[4];
  const float* w_xproj = (const float*)d_in[5];
  const float* A_log   = (const float*)d_in[6];
  const float* D_param = (const float*)d_in[7];
  const float* w_out   = (const float*)d_in[8];
  float* out = (float*)d_out;

  // workspace layout (bytes), ~157 MiB total
  char* ws = (char*)d_ws;
  size_t off = 0;
  float* proj  = (float*)(ws + off); off += (size_t)TOK * NPROJ * 4;     // 32.5 MiB
  f16*   xr16  = (f16*)(ws + off);   off += (size_t)TOK * DI * 2;        // 16 MiB (pre-conv x)
  f16*   z16   = (f16*)(ws + off);   off += (size_t)TOK * DI * 2;        // 16 MiB
  f16*   h16   = (f16*)(ws + off);   off += (size_t)TOK * HDIM * 2;      // 8 MiB
  f16*   xs16  = (f16*)(ws + off);   off += (size_t)TOK * DI * 2;        // 16 MiB
  f16*   yg16  = (f16*)(ws + off);   off += (size_t)TOK * DI * 2;        // 16 MiB
  f16*   winT  = (f16*)(ws + off);   off += (size_t)2 * DI * HDIM * 2;   // 8 MiB
  f16*   wxT   = (f16*)(ws + off);   off += (size_t)NPROJ * DI * 2;      // 8.5 MiB
  f16*   woT   = (f16*)(ws + off);   off += (size_t)HDIM * DI * 2;       // 4 MiB
  const size_t SCN = (size_t)NCH * BATCH * DI * DS;                      // 4M elems
  float* Atot  = (float*)(ws + off); off += SCN * 4;                     // 16 MiB (->Hin)
  float* Hend  = (float*)(ws + off); off += SCN * 4;                     // 16 MiB

  // 0. weight transpose+cast (f16, [N][K] row-major)
  k_transpose<<<dim3((2 * DI) / 32, HDIM / 32), 256, 0, stream>>>(w_in, winT, HDIM, 2 * DI);
  k_transpose<<<dim3(NPROJ / 32, DI / 32), 256, 0, stream>>>(w_xproj, wxT, DI, NPROJ);
  k_transpose<<<dim3(HDIM / 32, DI / 32), 256, 0, stream>>>(w_out, woT, DI, HDIM);
  // 1. RMSNorm -> h16
  k_rmsnorm<<<TOK, 256, 0, stream>>>(x, norm_w, h16);
  // 2. [xr16|z16] = h @ w_in  (BM=128: 32x32=1024 blocks, 4/CU)
  k_mgemm<3, 4><<<dim3((2 * DI) / 128, TOK / 128), 256, 0, stream>>>(
      h16, winT, nullptr, nullptr, xr16, z16, TOK, 2 * DI, HDIM);
  // 3. xs16 = silu(conv(xr16) + b)
  k_conv<<<(TOK * DI) / 256, 256, 0, stream>>>(xr16, conv_w, conv_b, xs16);
  // 4. proj = xs @ w_xproj (softplus cols>=32). BM=64: 17x64=1088 blocks, 4.25/CU
  k_mgemm<1, 2><<<dim3(17, TOK / 64), 256, 0, stream>>>(
      xs16, wxT, proj, nullptr, nullptr, nullptr, TOK, NPROJ, DI);
  // 5. chunked scan: A (per-chunk, reg-state), B (in-place stitch), C (+gate)
  const int NTH = NCH * BATCH * DI;                     // 262144 threads
  k_scanA<<<NTH / 256, 256, 0, stream>>>(proj, xs16, A_log, Atot, Hend);
  k_scanB<<<(BATCH * DI * DS) / 256, 256, 0, stream>>>(Atot, Hend);
  k_scanC<<<NTH / 256, 256, 0, stream>>>(proj, xs16, z16, A_log, D_param,
                                         Atot, yg16);
  // 6. out = x + yg @ w_out. BM=64: 8x64=512 blocks, 2/CU
  k_mgemm<2, 2><<<dim3(HDIM / 128, TOK / 64), 256, 0, stream>>>(
      yg16, woT, out, x, nullptr, nullptr, TOK, HDIM, DI);
}